// Round 2
// baseline (1722.821 us; speedup 1.0000x reference)
//
#include <hip/hip_runtime.h>
#include <hip/hip_bf16.h>

// GAT, H=4 heads x D=16, O=64 out channels, F=256 in features.
// Pipeline: wprep (W -> bf16 MFMA B-frags) -> proj_mfma (bf16 MFMA GEMM,
// fc -> fsb bf16 (head-aligned pair swizzle) + el/er logits, res -> out fp32)
// -> bucket_count (LDS hist over dst>>7) -> scan(3) over histT ->
// bucket_scatter (LDS-rank, packed (src<<7|dstlow) runs) ->
// agg_fused (per-bucket LDS fp32 accumulators, ds_add_f32 atomics,
//            consumes sorted_pk directly -- no per-bucket sort / CSR).
// NO global atomics anywhere in the main path.
// Softmax max-subtraction omitted: scores O(1), exp safe in fp32,
// softmax shift-invariant -> identical result.
//
// fsb swizzle (head-aligned): agg lane c (h=c>>3, j=c&7, hi2=h>>1) owns
//   ch0 = 16h + j + 8*hi2   (low  ushort of its dword, pos 2c)
//   ch1 = 16h + j + 8*(1-hi2) (high ushort, pos 2c+1)
// Both channels in head h -> ONE exp weight per lane is correct.
// ch0 % 32 and ch1 % 32 are each bijections over the half-wave ->
// both LDS atomics conflict-free per half (2-way per wave = free).

#define F_IN 256
#define O_OUT 64
#define NEG_SLOPE 0.2f
#define CHUNK 4096           // edges per block in bucket passes (782 blocks)
#define RMAX 2048            // max buckets supported by LDS hist

using frag_ab = __attribute__((ext_vector_type(8))) short;   // 8 bf16
using frag_cd = __attribute__((ext_vector_type(4))) float;   // 4 fp32

__device__ __forceinline__ float lrelu(float x) {
    return x >= 0.0f ? x : NEG_SLOPE * x;
}

__device__ __forceinline__ unsigned short f2bf(float f) {
    unsigned int u = __float_as_uint(f);
    unsigned int r = (u + 0x7fffu + ((u >> 16) & 1u)) >> 16;   // RNE
    return (unsigned short)r;
}
__device__ __forceinline__ float bflo(unsigned int p) {
    return __uint_as_float(p << 16);
}
__device__ __forceinline__ float bfhi(unsigned int p) {
    return __uint_as_float(p & 0xffff0000u);
}

// fsb position of channel ch under the head-aligned pair swizzle.
__device__ __forceinline__ int fsb_pos(int ch) {
    int h = ch >> 4;
    int jp = ch & 15;          // within-head index
    int hi2 = h >> 1;
    int jj = jp & 7;
    int c_lane = 8 * h + jj;
    // is_ch0: hi2==0 -> jp<8 ; hi2==1 -> jp>=8
    int is_ch0 = (hi2 == 0) ? (jp < 8) : (jp >= 8);
    return 2 * c_lane + (is_ch0 ? 0 : 1);
}

// ---------------------------------------------------------------------------
// Weight prep: Wfc/Wres fp32 [64][256] -> Bf bf16 in MFMA B-frag lane order.
// ---------------------------------------------------------------------------
__global__ __launch_bounds__(256) void wprep_kernel(
    const float* __restrict__ Wfc, const float* __restrict__ Wres,
    unsigned short* __restrict__ Bf)
{
    int tid = blockIdx.x * 256 + threadIdx.x;   // 0..4095
    int ct = tid >> 9;
    int lane = tid & 63;
    int ks = (tid >> 6) & 7;
    int col = ct * 16 + (lane & 15);
    int kbase = ks * 32 + (lane >> 4) * 8;
    const float* srcW = (col < 64) ? (Wfc + (size_t)col * 256 + kbase)
                                   : (Wres + (size_t)(col - 64) * 256 + kbase);
    unsigned short* dstp = Bf + (size_t)tid * 8;
#pragma unroll
    for (int i = 0; i < 8; ++i) dstp[i] = f2bf(srcW[i]);
}

// ---------------------------------------------------------------------------
// MFMA projection: block = 256 threads (4 waves), 64 nodes.
// ---------------------------------------------------------------------------
__global__ __launch_bounds__(256) void proj_mfma_kernel(
    const float* __restrict__ feat, const unsigned short* __restrict__ Bf,
    const float* __restrict__ attn_l, const float* __restrict__ attn_r,
    unsigned short* __restrict__ fsb, float* __restrict__ el,
    float* __restrict__ er, float* __restrict__ out,
    float* __restrict__ denom_zero, int N)
{
    __shared__ __align__(16) unsigned short sA[64 * 280];   // 35840 B
    const int t = threadIdx.x;
    const int lane = t & 63;
    const int w = t >> 6;
    const int n0 = blockIdx.x * 64;
    if (n0 >= N) return;

    frag_ab bfrag[2][8];
    {
        const unsigned short* bp = Bf + (size_t)lane * 8;
#pragma unroll
        for (int j = 0; j < 2; ++j)
#pragma unroll
            for (int ks = 0; ks < 8; ++ks)
                bfrag[j][ks] = *(const frag_ab*)(bp + (size_t)((2 * w + j) * 8 + ks) * 512);
    }

    if (denom_zero && n0 * 4 + t < N * 4) denom_zero[n0 * 4 + t] = 0.0f;

    for (int i = 0; i < 8; ++i) {
        int f = i * 256 + t;
        int row = f >> 5, c8 = f & 31;
        int n = n0 + row;
        float4 v0 = make_float4(0.f, 0.f, 0.f, 0.f), v1 = v0;
        if (n < N) {
            const float4* p = (const float4*)(feat + (size_t)n * F_IN + c8 * 8);
            v0 = p[0]; v1 = p[1];
        }
        frag_ab pack;
        pack[0] = (short)f2bf(v0.x); pack[1] = (short)f2bf(v0.y);
        pack[2] = (short)f2bf(v0.z); pack[3] = (short)f2bf(v0.w);
        pack[4] = (short)f2bf(v1.x); pack[5] = (short)f2bf(v1.y);
        pack[6] = (short)f2bf(v1.z); pack[7] = (short)f2bf(v1.w);
        *(frag_ab*)(&sA[row * 280 + c8 * 8]) = pack;
    }
    __syncthreads();

    frag_cd acc[4][2];
#pragma unroll
    for (int rt = 0; rt < 4; ++rt)
#pragma unroll
        for (int j = 0; j < 2; ++j)
            acc[rt][j] = (frag_cd){0.f, 0.f, 0.f, 0.f};

#pragma unroll
    for (int ks = 0; ks < 8; ++ks) {
        frag_ab af[4];
#pragma unroll
        for (int rt = 0; rt < 4; ++rt) {
            int row = rt * 16 + (lane & 15);
            int c8 = ks * 4 + (lane >> 4);
            af[rt] = *(const frag_ab*)(&sA[row * 280 + c8 * 8]);
        }
#pragma unroll
        for (int rt = 0; rt < 4; ++rt)
#pragma unroll
            for (int j = 0; j < 2; ++j)
                acc[rt][j] = __builtin_amdgcn_mfma_f32_16x16x32_bf16(
                    af[rt], bfrag[j][ks], acc[rt][j], 0, 0, 0);
    }

    // epilogue: C/D layout col = lane&15, row = (lane>>4)*4 + reg  [m89]
    const int colq = lane & 15;
    const int quad = lane >> 4;
    if (w < 2) {
#pragma unroll
        for (int j = 0; j < 2; ++j) {
            int h = 2 * w + j;
            float al = attn_l[h * 16 + colq];
            float ar = attn_r[h * 16 + colq];
            int pos = fsb_pos(h * 16 + colq);    // head-aligned pair swizzle
#pragma unroll
            for (int rt = 0; rt < 4; ++rt)
#pragma unroll
                for (int r = 0; r < 4; ++r) {
                    int node = n0 + rt * 16 + quad * 4 + r;
                    float v = acc[rt][j][r];
                    if (node < N) fsb[(size_t)node * O_OUT + pos] = f2bf(v);
                    float pl = v * al, pr = v * ar;
                    pl += __shfl_xor(pl, 1); pr += __shfl_xor(pr, 1);
                    pl += __shfl_xor(pl, 2); pr += __shfl_xor(pr, 2);
                    pl += __shfl_xor(pl, 4); pr += __shfl_xor(pr, 4);
                    pl += __shfl_xor(pl, 8); pr += __shfl_xor(pr, 8);
                    if (colq == 0 && node < N) {
                        el[(size_t)node * 4 + h] = pl;
                        er[(size_t)node * 4 + h] = pr;
                    }
                }
        }
    } else {
#pragma unroll
        for (int j = 0; j < 2; ++j) {
            int cb = 32 * (w - 2) + 16 * j;
#pragma unroll
            for (int rt = 0; rt < 4; ++rt)
#pragma unroll
                for (int r = 0; r < 4; ++r) {
                    int node = n0 + rt * 16 + quad * 4 + r;
                    if (node < N)
                        out[(size_t)node * O_OUT + cb + colq] = acc[rt][j][r];
                }
        }
    }
}

// ---------------------------------------------------------------------------
// Bucket pass A: per-block LDS histogram of dst>>7 -> histT[bin*B + b].
// ---------------------------------------------------------------------------
__global__ __launch_bounds__(256) void bucket_count_kernel(
    const int* __restrict__ dst, int* __restrict__ histT, int E, int B, int R)
{
    __shared__ int h[RMAX];
    int b = blockIdx.x, t = threadIdx.x;
    for (int i = t; i < R; i += 256) h[i] = 0;
    __syncthreads();
    int base = b * CHUNK;
    for (int i = t; i < CHUNK; i += 256) {
        int e = base + i;
        if (e < E) atomicAdd(&h[dst[e] >> 7], 1);
    }
    __syncthreads();
    for (int i = t; i < R; i += 256) histT[(size_t)i * B + b] = h[i];
}

// ---------------------------------------------------------------------------
// Scan chain (exclusive prefix sum over arbitrary n, 1024/block).
// ---------------------------------------------------------------------------
__global__ __launch_bounds__(256) void scan_block_kernel(
    const int* __restrict__ counts, int* __restrict__ outp,
    int* __restrict__ bsums, int n)
{
    int t = threadIdx.x;
    int base = blockIdx.x * 1024 + t * 4;
    int c0 = 0, c1 = 0, c2 = 0, c3 = 0;
    if (base + 3 < n) {
        int4 v = *(const int4*)(counts + base);
        c0 = v.x; c1 = v.y; c2 = v.z; c3 = v.w;
    } else {
        if (base     < n) c0 = counts[base];
        if (base + 1 < n) c1 = counts[base + 1];
        if (base + 2 < n) c2 = counts[base + 2];
        if (base + 3 < n) c3 = counts[base + 3];
    }
    int tsum = c0 + c1 + c2 + c3;
    int inc = tsum;
    int lane = t & 63, wid = t >> 6;
#pragma unroll
    for (int o = 1; o < 64; o <<= 1) {
        int v = __shfl_up(inc, o);
        if (lane >= o) inc += v;
    }
    __shared__ int wsum[4];
    if (lane == 63) wsum[wid] = inc;
    __syncthreads();
    int woff = 0;
#pragma unroll
    for (int w = 0; w < 4; ++w)
        if (w < wid) woff += wsum[w];
    int excl = woff + inc - tsum;
    int e0 = excl, e1 = excl + c0, e2 = e1 + c1, e3 = e2 + c2;
    if (base + 3 < n) {
        *(int4*)(outp + base) = make_int4(e0, e1, e2, e3);
    } else {
        if (base     < n) outp[base]     = e0;
        if (base + 1 < n) outp[base + 1] = e1;
        if (base + 2 < n) outp[base + 2] = e2;
        if (base + 3 < n) outp[base + 3] = e3;
    }
    if (t == 255) bsums[blockIdx.x] = wsum[0] + wsum[1] + wsum[2] + wsum[3];
}

__global__ void scan_bsums_kernel(int* __restrict__ bsums, int nb)
{
    int lane = threadIdx.x;   // 64 threads
    int carry = 0;
    for (int c = 0; c * 64 < nb; ++c) {
        int i = c * 64 + lane;
        int v = (i < nb) ? bsums[i] : 0;
        int inc = v;
#pragma unroll
        for (int o = 1; o < 64; o <<= 1) {
            int u = __shfl_up(inc, o);
            if (lane >= o) inc += u;
        }
        if (i < nb) bsums[i] = carry + inc - v;
        carry += __shfl(inc, 63);
    }
}

__global__ __launch_bounds__(256) void scan_final_kernel(
    int* __restrict__ outp, const int* __restrict__ bsums, int n, int total)
{
    int i = blockIdx.x * 256 + threadIdx.x;
    if (i < n) outp[i] = outp[i] + bsums[i >> 10];
    if (i == 0) outp[n] = total;   // outp must have n+1 capacity
}

// ---------------------------------------------------------------------------
// Bucket pass C: LDS-atomic local rank; write packed (src<<7)|dstlow to
// sorted_pk at histS[bin*B+b] + rank. Per-bucket runs are contiguous.
// ---------------------------------------------------------------------------
__global__ __launch_bounds__(256) void bucket_scatter_kernel(
    const int* __restrict__ src, const int* __restrict__ dst,
    const int* __restrict__ histS, unsigned int* __restrict__ sorted_pk,
    int E, int B, int R)
{
    __shared__ int h[RMAX];
    __shared__ int basebin[RMAX];
    int b = blockIdx.x, t = threadIdx.x;
    for (int i = t; i < R; i += 256) {
        h[i] = 0;
        basebin[i] = histS[(size_t)i * B + b];
    }
    __syncthreads();
    int base = b * CHUNK;
    for (int i = t; i < CHUNK; i += 256) {
        int e = base + i;
        if (e < E) {
            int d = dst[e];
            int bin = d >> 7;
            int rk = atomicAdd(&h[bin], 1);
            sorted_pk[basebin[bin] + rk] =
                ((unsigned int)src[e] << 7) | (unsigned int)(d & 127);
        }
    }
}

// ---------------------------------------------------------------------------
// Fused aggregation: one block per bucket (128 dst nodes), 512 threads.
// LDS fp32 accumulators (num[128][64] + den[128][4]) fed by ds_add_f32;
// consumes sorted_pk runs directly (no per-bucket sort, no CSR arrays).
// Each half-wave owns one edge; lane c owns head-aligned channel pair
// (ch0, ch1) -- see swizzle comment at top. One exp per lane (head c>>3).
// ---------------------------------------------------------------------------
__global__ __launch_bounds__(512) void agg_fused_kernel(
    const int* __restrict__ histS, const unsigned int* __restrict__ sorted_pk,
    const unsigned short* __restrict__ fsb, const float* __restrict__ el,
    const float* __restrict__ er, float* __restrict__ out,
    int N, int E, int B, int R)
{
    __shared__ float num[128][64];    // 32 KiB
    __shared__ float den[128][4];     // 2 KiB
    __shared__ float er_s[512];       // 2 KiB
    const int r = blockIdx.x;
    const int t = threadIdx.x;

    float* np = &num[0][0];
    for (int i = t; i < 128 * 64; i += 512) np[i] = 0.f;
    ((float*)den)[t] = 0.f;                       // 512 floats exactly
    int gn = r * 512 + t;
    er_s[t] = (gn < N * 4) ? er[gn] : 0.f;
    __syncthreads();

    const int start = histS[(size_t)r * B];
    const int end = (r + 1 < R) ? histS[(size_t)(r + 1) * B] : E;
    const int lane = t & 63;
    const int wid = t >> 6;            // 0..7
    const int half = lane >> 5;
    const int c = lane & 31;
    const int h = c >> 3;
    const int hi2 = h >> 1;
    const int ch0 = 16 * h + (c & 7) + 8 * hi2;        // bijective mod 32
    const int ch1 = 16 * h + (c & 7) + 8 * (1 - hi2);  // bijective mod 32

    // main loop: 16 edges (8 pairs) per wave iteration, 8 fsb loads in flight
    int kb = start + wid * 16;
    for (; kb + 16 <= end; kb += 8 * 16) {
        unsigned int pk[8];
#pragma unroll
        for (int p = 0; p < 8; ++p) pk[p] = sorted_pk[kb + 2 * p + half];
        float elv[8]; unsigned int fv[8]; int dl[8];
#pragma unroll
        for (int p = 0; p < 8; ++p) {
            int s = (int)(pk[p] >> 7);
            dl[p] = (int)(pk[p] & 127u);
            elv[p] = el[(size_t)s * 4 + h];
            fv[p] = *(const unsigned int*)(fsb + (size_t)s * O_OUT + 2 * c);
        }
#pragma unroll
        for (int p = 0; p < 8; ++p) {
            float wv = __expf(lrelu(elv[p] + er_s[dl[p] * 4 + h]));
            atomicAdd(&num[dl[p]][ch0], wv * bflo(fv[p]));
            atomicAdd(&num[dl[p]][ch1], wv * bfhi(fv[p]));
            if ((c & 7) == 0) atomicAdd(&den[dl[p]][h], wv);
        }
    }
    // tail: < 16 leftover edges, wave 0 only
    {
        int tb = start + ((end - start) & ~15);
        if (wid == 0) {
            for (int kb2 = tb + half; kb2 < end; kb2 += 2) {
                unsigned int pk = sorted_pk[kb2];
                int s = (int)(pk >> 7);
                int dl2 = (int)(pk & 127u);
                float wv = __expf(lrelu(el[(size_t)s * 4 + h] + er_s[dl2 * 4 + h]));
                unsigned int f = *(const unsigned int*)(fsb + (size_t)s * O_OUT + 2 * c);
                atomicAdd(&num[dl2][ch0], wv * bflo(f));
                atomicAdd(&num[dl2][ch1], wv * bfhi(f));
                if ((c & 7) == 0) atomicAdd(&den[dl2][h], wv);
            }
        }
    }
    __syncthreads();

    // epilogue: out[node] += num/den (out already holds resval from proj)
#pragma unroll
    for (int i = 0; i < 4; ++i) {
        int idx = i * 2048 + t * 4;        // 0..8188, step 4
        int row = idx >> 6;
        int ch = idx & 63;                 // multiple of 4, h-group uniform
        int node = r * 128 + row;
        if (node < N) {
            float inv = 1.0f / fmaxf(den[row][ch >> 4], 1e-20f);
            float4 v = *(const float4*)(&num[row][ch]);
            float4* po = (float4*)(out + (size_t)node * O_OUT + ch);
            float4 o = *po;
            o.x += v.x * inv; o.y += v.y * inv;
            o.z += v.z * inv; o.w += v.w * inv;
            *po = o;
        }
    }
}

// ---------------------------------------------------------------------------
// Fallback path (small ws): no-max softmax, atomics, bf16 fs.
// ---------------------------------------------------------------------------
__global__ __launch_bounds__(256) void edge_sum_kernel(
    const int* __restrict__ src, const int* __restrict__ dst,
    const float* __restrict__ el, const float* __restrict__ er,
    float* __restrict__ denom, int E)
{
    int e = blockIdx.x * 256 + threadIdx.x;
    if (e >= E) return;
    int s = src[e], d = dst[e];
    float4 l4 = ((const float4*)el)[s];
    float4 r4 = ((const float4*)er)[d];
    unsafeAtomicAdd(&denom[(size_t)d * 4 + 0], __expf(lrelu(l4.x + r4.x)));
    unsafeAtomicAdd(&denom[(size_t)d * 4 + 1], __expf(lrelu(l4.y + r4.y)));
    unsafeAtomicAdd(&denom[(size_t)d * 4 + 2], __expf(lrelu(l4.z + r4.z)));
    unsafeAtomicAdd(&denom[(size_t)d * 4 + 3], __expf(lrelu(l4.w + r4.w)));
}

__global__ __launch_bounds__(256) void agg_atomic_kernel(
    const int* __restrict__ src, const int* __restrict__ dst,
    const unsigned short* __restrict__ fsb, const float* __restrict__ el,
    const float* __restrict__ er, const float* __restrict__ denom,
    float* __restrict__ out, int E)
{
    const int lane = threadIdx.x & 63;
    const int wid = threadIdx.x >> 6;
    int e = blockIdx.x * 4 + wid;
    if (e >= E) return;
    int s = src[e], d = dst[e];
    // invert head-aligned pair swizzle: position `lane` -> channel ch
    int h = lane >> 4;                 // head of this position
    int jj = (lane >> 1) & 7;
    int hi2 = (lane >> 5) & 1;
    int odd = lane & 1;
    int ch = 16 * h + jj + 8 * (hi2 ^ odd);
    float v = __expf(lrelu(el[(size_t)s * 4 + h] + er[(size_t)d * 4 + h]));
    float alpha = v / fmaxf(denom[(size_t)d * 4 + h], 1e-20f);
    float fval = __uint_as_float(((unsigned int)fsb[(size_t)s * O_OUT + lane]) << 16);
    unsafeAtomicAdd(&out[(size_t)d * O_OUT + ch], alpha * fval);
}

extern "C" void kernel_launch(void* const* d_in, const int* in_sizes, int n_in,
                              void* d_out, int out_size, void* d_ws, size_t ws_size,
                              hipStream_t stream) {
    const float* feat   = (const float*)d_in[0];
    const float* Wfc    = (const float*)d_in[1];
    const float* attn_l = (const float*)d_in[2];
    const float* attn_r = (const float*)d_in[3];
    const float* Wres   = (const float*)d_in[4];
    const int*   src    = (const int*)d_in[5];
    const int*   dst    = (const int*)d_in[6];

    const int N = in_sizes[0] / F_IN;     // 100000
    const int E = in_sizes[5];            // 3200000
    float* out = (float*)d_out;

    const int R = (N + 127) >> 7;                 // buckets of 128 nodes
    const int B = (E + CHUNK - 1) / CHUNK;        // blocks in bucket passes
    const int nRB = R * B;
    const int nsb = (nRB + 1023) / 1024;

    // layout: el | er | Bf | histT[nRB] | histS[nRB+8] | bsums[1024] |
    //         sorted_pk[E] | fsb
    float* el     = (float*)d_ws;
    float* er     = el + (size_t)N * 4;
    unsigned short* Bf = (unsigned short*)(er + (size_t)N * 4);
    int*   histT  = (int*)(Bf + 32768);
    int*   histS  = histT + nRB;
    int*   bsums  = histS + nRB + 8;
    unsigned int* sorted_pk = (unsigned int*)(bsums + 1024);
    unsigned short* fsb = (unsigned short*)(sorted_pk + E);
    size_t need_main = (size_t)((char*)(fsb + (size_t)N * O_OUT) - (char*)d_ws);

    int nproj = (N + 63) / 64;

    if (ws_size >= need_main && R <= RMAX && nsb <= 1024) {
        wprep_kernel<<<16, 256, 0, stream>>>(Wfc, Wres, Bf);
        proj_mfma_kernel<<<nproj, 256, 0, stream>>>(
            feat, Bf, attn_l, attn_r, fsb, el, er, out, nullptr, N);
        bucket_count_kernel<<<B, 256, 0, stream>>>(dst, histT, E, B, R);
        scan_block_kernel<<<nsb, 256, 0, stream>>>(histT, histS, bsums, nRB);
        scan_bsums_kernel<<<1, 64, 0, stream>>>(bsums, nsb);
        scan_final_kernel<<<(nRB + 255) / 256, 256, 0, stream>>>(histS, bsums, nRB, E);
        bucket_scatter_kernel<<<B, 256, 0, stream>>>(src, dst, histS, sorted_pk, E, B, R);
        agg_fused_kernel<<<R, 512, 0, stream>>>(
            histS, sorted_pk, fsb, el, er, out, N, E, B, R);
    } else {
        // fallback: denom overlays histT region; fsb right after denom
        float* denom = (float*)histT;                 // [N*4]
        unsigned short* fsb2 = (unsigned short*)(denom + (size_t)N * 4);
        wprep_kernel<<<16, 256, 0, stream>>>(Wfc, Wres, Bf);
        proj_mfma_kernel<<<nproj, 256, 0, stream>>>(
            feat, Bf, attn_l, attn_r, fsb2, el, er, out, denom, N);
        edge_sum_kernel<<<(E + 255) / 256, 256, 0, stream>>>(src, dst, el, er, denom, E);
        agg_atomic_kernel<<<(E + 3) / 4, 256, 0, stream>>>(
            src, dst, fsb2, el, er, denom, out, E);
    }
}

// Round 3
// 1720.827 us; speedup vs baseline: 1.0012x; 1.0012x over previous
//
#include <hip/hip_runtime.h>
#include <hip/hip_bf16.h>

// GAT, H=4 heads x D=16, O=64 out channels, F=256 in features.
// Pipeline: wprep (W -> bf16 MFMA B-frags) -> proj_mfma (bf16 MFMA GEMM,
// fc -> fsb bf16 (head-aligned pair swizzle) + el/er logits, res -> out fp32)
// -> bucket_count (LDS hist over dst>>7) -> scan(3) over histT ->
// bucket_scatter (LDS-rank, packed (src<<7|dstlow) runs) ->
// agg_fused (per-bucket LDS fp32 accumulators, ds_add_f32 atomics,
//            consumes sorted_pk directly -- no per-bucket sort / CSR).
// NO global atomics anywhere in the main path.
// Softmax max-subtraction omitted: scores O(1), exp safe in fp32,
// softmax shift-invariant -> identical result.
//
// agg_fused inner loop uses NAMED SCALARS ONLY -- round-2 version used
// pk[8]/elv[8]/fv[8] arrays which the compiler demoted to scratch
// (VGPR_Count=24, 12x slowdown, pitfall #20). Never index arrays here.
//
// fsb swizzle (head-aligned): agg lane c (h=c>>3, j=c&7, hi2=h>>1) owns
//   ch0 = 16h + j + 8*hi2     (low  ushort of its dword, pos 2c)
//   ch1 = 16h + j + 8*(1-hi2) (high ushort, pos 2c+1)
// Both channels in head h -> ONE exp weight per lane is correct.
// ch0 % 32 and ch1 % 32 are each bijections over the half-wave ->
// both LDS atomics conflict-free per half (2-way per wave = free).

#define F_IN 256
#define O_OUT 64
#define NEG_SLOPE 0.2f
#define CHUNK 4096           // edges per block in bucket passes (782 blocks)
#define RMAX 2048            // max buckets supported by LDS hist

using frag_ab = __attribute__((ext_vector_type(8))) short;   // 8 bf16
using frag_cd = __attribute__((ext_vector_type(4))) float;   // 4 fp32

__device__ __forceinline__ float lrelu(float x) {
    return x >= 0.0f ? x : NEG_SLOPE * x;
}

__device__ __forceinline__ unsigned short f2bf(float f) {
    unsigned int u = __float_as_uint(f);
    unsigned int r = (u + 0x7fffu + ((u >> 16) & 1u)) >> 16;   // RNE
    return (unsigned short)r;
}
__device__ __forceinline__ float bflo(unsigned int p) {
    return __uint_as_float(p << 16);
}
__device__ __forceinline__ float bfhi(unsigned int p) {
    return __uint_as_float(p & 0xffff0000u);
}

// fsb position of channel ch under the head-aligned pair swizzle.
__device__ __forceinline__ int fsb_pos(int ch) {
    int h = ch >> 4;
    int jp = ch & 15;          // within-head index
    int hi2 = h >> 1;
    int jj = jp & 7;
    int c_lane = 8 * h + jj;
    // is_ch0: hi2==0 -> jp<8 ; hi2==1 -> jp>=8
    int is_ch0 = (hi2 == 0) ? (jp < 8) : (jp >= 8);
    return 2 * c_lane + (is_ch0 ? 0 : 1);
}

// ---------------------------------------------------------------------------
// Weight prep: Wfc/Wres fp32 [64][256] -> Bf bf16 in MFMA B-frag lane order.
// ---------------------------------------------------------------------------
__global__ __launch_bounds__(256) void wprep_kernel(
    const float* __restrict__ Wfc, const float* __restrict__ Wres,
    unsigned short* __restrict__ Bf)
{
    int tid = blockIdx.x * 256 + threadIdx.x;   // 0..4095
    int ct = tid >> 9;
    int lane = tid & 63;
    int ks = (tid >> 6) & 7;
    int col = ct * 16 + (lane & 15);
    int kbase = ks * 32 + (lane >> 4) * 8;
    const float* srcW = (col < 64) ? (Wfc + (size_t)col * 256 + kbase)
                                   : (Wres + (size_t)(col - 64) * 256 + kbase);
    unsigned short* dstp = Bf + (size_t)tid * 8;
#pragma unroll
    for (int i = 0; i < 8; ++i) dstp[i] = f2bf(srcW[i]);
}

// ---------------------------------------------------------------------------
// MFMA projection: block = 256 threads (4 waves), 64 nodes.
// ---------------------------------------------------------------------------
__global__ __launch_bounds__(256) void proj_mfma_kernel(
    const float* __restrict__ feat, const unsigned short* __restrict__ Bf,
    const float* __restrict__ attn_l, const float* __restrict__ attn_r,
    unsigned short* __restrict__ fsb, float* __restrict__ el,
    float* __restrict__ er, float* __restrict__ out,
    float* __restrict__ denom_zero, int N)
{
    __shared__ __align__(16) unsigned short sA[64 * 280];   // 35840 B
    const int t = threadIdx.x;
    const int lane = t & 63;
    const int w = t >> 6;
    const int n0 = blockIdx.x * 64;
    if (n0 >= N) return;

    frag_ab bfrag[2][8];
    {
        const unsigned short* bp = Bf + (size_t)lane * 8;
#pragma unroll
        for (int j = 0; j < 2; ++j)
#pragma unroll
            for (int ks = 0; ks < 8; ++ks)
                bfrag[j][ks] = *(const frag_ab*)(bp + (size_t)((2 * w + j) * 8 + ks) * 512);
    }

    if (denom_zero && n0 * 4 + t < N * 4) denom_zero[n0 * 4 + t] = 0.0f;

    for (int i = 0; i < 8; ++i) {
        int f = i * 256 + t;
        int row = f >> 5, c8 = f & 31;
        int n = n0 + row;
        float4 v0 = make_float4(0.f, 0.f, 0.f, 0.f), v1 = v0;
        if (n < N) {
            const float4* p = (const float4*)(feat + (size_t)n * F_IN + c8 * 8);
            v0 = p[0]; v1 = p[1];
        }
        frag_ab pack;
        pack[0] = (short)f2bf(v0.x); pack[1] = (short)f2bf(v0.y);
        pack[2] = (short)f2bf(v0.z); pack[3] = (short)f2bf(v0.w);
        pack[4] = (short)f2bf(v1.x); pack[5] = (short)f2bf(v1.y);
        pack[6] = (short)f2bf(v1.z); pack[7] = (short)f2bf(v1.w);
        *(frag_ab*)(&sA[row * 280 + c8 * 8]) = pack;
    }
    __syncthreads();

    frag_cd acc[4][2];
#pragma unroll
    for (int rt = 0; rt < 4; ++rt)
#pragma unroll
        for (int j = 0; j < 2; ++j)
            acc[rt][j] = (frag_cd){0.f, 0.f, 0.f, 0.f};

#pragma unroll
    for (int ks = 0; ks < 8; ++ks) {
        frag_ab af[4];
#pragma unroll
        for (int rt = 0; rt < 4; ++rt) {
            int row = rt * 16 + (lane & 15);
            int c8 = ks * 4 + (lane >> 4);
            af[rt] = *(const frag_ab*)(&sA[row * 280 + c8 * 8]);
        }
#pragma unroll
        for (int rt = 0; rt < 4; ++rt)
#pragma unroll
            for (int j = 0; j < 2; ++j)
                acc[rt][j] = __builtin_amdgcn_mfma_f32_16x16x32_bf16(
                    af[rt], bfrag[j][ks], acc[rt][j], 0, 0, 0);
    }

    // epilogue: C/D layout col = lane&15, row = (lane>>4)*4 + reg  [m89]
    const int colq = lane & 15;
    const int quad = lane >> 4;
    if (w < 2) {
#pragma unroll
        for (int j = 0; j < 2; ++j) {
            int h = 2 * w + j;
            float al = attn_l[h * 16 + colq];
            float ar = attn_r[h * 16 + colq];
            int pos = fsb_pos(h * 16 + colq);    // head-aligned pair swizzle
#pragma unroll
            for (int rt = 0; rt < 4; ++rt)
#pragma unroll
                for (int r = 0; r < 4; ++r) {
                    int node = n0 + rt * 16 + quad * 4 + r;
                    float v = acc[rt][j][r];
                    if (node < N) fsb[(size_t)node * O_OUT + pos] = f2bf(v);
                    float pl = v * al, pr = v * ar;
                    pl += __shfl_xor(pl, 1); pr += __shfl_xor(pr, 1);
                    pl += __shfl_xor(pl, 2); pr += __shfl_xor(pr, 2);
                    pl += __shfl_xor(pl, 4); pr += __shfl_xor(pr, 4);
                    pl += __shfl_xor(pl, 8); pr += __shfl_xor(pr, 8);
                    if (colq == 0 && node < N) {
                        el[(size_t)node * 4 + h] = pl;
                        er[(size_t)node * 4 + h] = pr;
                    }
                }
        }
    } else {
#pragma unroll
        for (int j = 0; j < 2; ++j) {
            int cb = 32 * (w - 2) + 16 * j;
#pragma unroll
            for (int rt = 0; rt < 4; ++rt)
#pragma unroll
                for (int r = 0; r < 4; ++r) {
                    int node = n0 + rt * 16 + quad * 4 + r;
                    if (node < N)
                        out[(size_t)node * O_OUT + cb + colq] = acc[rt][j][r];
                }
        }
    }
}

// ---------------------------------------------------------------------------
// Bucket pass A: per-block LDS histogram of dst>>7 -> histT[bin*B + b].
// ---------------------------------------------------------------------------
__global__ __launch_bounds__(256) void bucket_count_kernel(
    const int* __restrict__ dst, int* __restrict__ histT, int E, int B, int R)
{
    __shared__ int h[RMAX];
    int b = blockIdx.x, t = threadIdx.x;
    for (int i = t; i < R; i += 256) h[i] = 0;
    __syncthreads();
    int base = b * CHUNK;
    for (int i = t; i < CHUNK; i += 256) {
        int e = base + i;
        if (e < E) atomicAdd(&h[dst[e] >> 7], 1);
    }
    __syncthreads();
    for (int i = t; i < R; i += 256) histT[(size_t)i * B + b] = h[i];
}

// ---------------------------------------------------------------------------
// Scan chain (exclusive prefix sum over arbitrary n, 1024/block).
// ---------------------------------------------------------------------------
__global__ __launch_bounds__(256) void scan_block_kernel(
    const int* __restrict__ counts, int* __restrict__ outp,
    int* __restrict__ bsums, int n)
{
    int t = threadIdx.x;
    int base = blockIdx.x * 1024 + t * 4;
    int c0 = 0, c1 = 0, c2 = 0, c3 = 0;
    if (base + 3 < n) {
        int4 v = *(const int4*)(counts + base);
        c0 = v.x; c1 = v.y; c2 = v.z; c3 = v.w;
    } else {
        if (base     < n) c0 = counts[base];
        if (base + 1 < n) c1 = counts[base + 1];
        if (base + 2 < n) c2 = counts[base + 2];
        if (base + 3 < n) c3 = counts[base + 3];
    }
    int tsum = c0 + c1 + c2 + c3;
    int inc = tsum;
    int lane = t & 63, wid = t >> 6;
#pragma unroll
    for (int o = 1; o < 64; o <<= 1) {
        int v = __shfl_up(inc, o);
        if (lane >= o) inc += v;
    }
    __shared__ int wsum[4];
    if (lane == 63) wsum[wid] = inc;
    __syncthreads();
    int woff = 0;
#pragma unroll
    for (int w = 0; w < 4; ++w)
        if (w < wid) woff += wsum[w];
    int excl = woff + inc - tsum;
    int e0 = excl, e1 = excl + c0, e2 = e1 + c1, e3 = e2 + c2;
    if (base + 3 < n) {
        *(int4*)(outp + base) = make_int4(e0, e1, e2, e3);
    } else {
        if (base     < n) outp[base]     = e0;
        if (base + 1 < n) outp[base + 1] = e1;
        if (base + 2 < n) outp[base + 2] = e2;
        if (base + 3 < n) outp[base + 3] = e3;
    }
    if (t == 255) bsums[blockIdx.x] = wsum[0] + wsum[1] + wsum[2] + wsum[3];
}

__global__ void scan_bsums_kernel(int* __restrict__ bsums, int nb)
{
    int lane = threadIdx.x;   // 64 threads
    int carry = 0;
    for (int c = 0; c * 64 < nb; ++c) {
        int i = c * 64 + lane;
        int v = (i < nb) ? bsums[i] : 0;
        int inc = v;
#pragma unroll
        for (int o = 1; o < 64; o <<= 1) {
            int u = __shfl_up(inc, o);
            if (lane >= o) inc += u;
        }
        if (i < nb) bsums[i] = carry + inc - v;
        carry += __shfl(inc, 63);
    }
}

__global__ __launch_bounds__(256) void scan_final_kernel(
    int* __restrict__ outp, const int* __restrict__ bsums, int n, int total)
{
    int i = blockIdx.x * 256 + threadIdx.x;
    if (i < n) outp[i] = outp[i] + bsums[i >> 10];
    if (i == 0) outp[n] = total;   // outp must have n+1 capacity
}

// ---------------------------------------------------------------------------
// Bucket pass C: LDS-atomic local rank; write packed (src<<7)|dstlow to
// sorted_pk at histS[bin*B+b] + rank. Per-bucket runs are contiguous.
// ---------------------------------------------------------------------------
__global__ __launch_bounds__(256) void bucket_scatter_kernel(
    const int* __restrict__ src, const int* __restrict__ dst,
    const int* __restrict__ histS, unsigned int* __restrict__ sorted_pk,
    int E, int B, int R)
{
    __shared__ int h[RMAX];
    __shared__ int basebin[RMAX];
    int b = blockIdx.x, t = threadIdx.x;
    for (int i = t; i < R; i += 256) {
        h[i] = 0;
        basebin[i] = histS[(size_t)i * B + b];
    }
    __syncthreads();
    int base = b * CHUNK;
    for (int i = t; i < CHUNK; i += 256) {
        int e = base + i;
        if (e < E) {
            int d = dst[e];
            int bin = d >> 7;
            int rk = atomicAdd(&h[bin], 1);
            sorted_pk[basebin[bin] + rk] =
                ((unsigned int)src[e] << 7) | (unsigned int)(d & 127);
        }
    }
}

// ---------------------------------------------------------------------------
// Fused aggregation: one block per bucket (128 dst nodes), 512 threads.
// LDS fp32 accumulators (num[128][64] + den[128][4]) fed by ds_add_f32;
// consumes sorted_pk runs directly (no per-bucket sort, no CSR arrays).
// Each half-wave owns one edge; 4 edge-pairs per wave-iteration with
// NAMED SCALARS (no arrays -> no scratch demotion, pitfall #20).
// ---------------------------------------------------------------------------
__global__ __launch_bounds__(512) void agg_fused_kernel(
    const int* __restrict__ histS, const unsigned int* __restrict__ sorted_pk,
    const unsigned short* __restrict__ fsb, const float* __restrict__ el,
    const float* __restrict__ er, float* __restrict__ out,
    int N, int E, int B, int R)
{
    __shared__ float num[128][64];    // 32 KiB
    __shared__ float den[128][4];     // 2 KiB
    __shared__ float er_s[512];       // 2 KiB
    const int r = blockIdx.x;
    const int t = threadIdx.x;

    float* np = &num[0][0];
    for (int i = t; i < 128 * 64; i += 512) np[i] = 0.f;
    ((float*)den)[t] = 0.f;                       // 512 floats exactly
    int gn = r * 512 + t;
    er_s[t] = (gn < N * 4) ? er[gn] : 0.f;
    __syncthreads();

    const int start = histS[(size_t)r * B];
    const int end = (r + 1 < R) ? histS[(size_t)(r + 1) * B] : E;
    const int lane = t & 63;
    const int wid = t >> 6;            // 0..7
    const int half = lane >> 5;
    const int c = lane & 31;
    const int h = c >> 3;
    const int hi2 = h >> 1;
    const int ch0 = 16 * h + (c & 7) + 8 * hi2;        // bijective mod 32
    const int ch1 = 16 * h + (c & 7) + 8 * (1 - hi2);  // bijective mod 32

    // main loop: 8 edges (4 pairs) per wave iteration; phase-split loads.
    int kb = start + wid * 8;
    for (; kb + 8 <= end; kb += 8 * 8) {
        unsigned int pk0 = sorted_pk[kb + 0 + half];
        unsigned int pk1 = sorted_pk[kb + 2 + half];
        unsigned int pk2 = sorted_pk[kb + 4 + half];
        unsigned int pk3 = sorted_pk[kb + 6 + half];
        int s0 = (int)(pk0 >> 7), dl0 = (int)(pk0 & 127u);
        int s1 = (int)(pk1 >> 7), dl1 = (int)(pk1 & 127u);
        int s2 = (int)(pk2 >> 7), dl2 = (int)(pk2 & 127u);
        int s3 = (int)(pk3 >> 7), dl3 = (int)(pk3 & 127u);
        float ea0 = el[(size_t)s0 * 4 + h];
        float ea1 = el[(size_t)s1 * 4 + h];
        float ea2 = el[(size_t)s2 * 4 + h];
        float ea3 = el[(size_t)s3 * 4 + h];
        unsigned int f0 = *(const unsigned int*)(fsb + (size_t)s0 * O_OUT + 2 * c);
        unsigned int f1 = *(const unsigned int*)(fsb + (size_t)s1 * O_OUT + 2 * c);
        unsigned int f2 = *(const unsigned int*)(fsb + (size_t)s2 * O_OUT + 2 * c);
        unsigned int f3 = *(const unsigned int*)(fsb + (size_t)s3 * O_OUT + 2 * c);
        float w0 = __expf(lrelu(ea0 + er_s[dl0 * 4 + h]));
        float w1 = __expf(lrelu(ea1 + er_s[dl1 * 4 + h]));
        float w2 = __expf(lrelu(ea2 + er_s[dl2 * 4 + h]));
        float w3 = __expf(lrelu(ea3 + er_s[dl3 * 4 + h]));
        atomicAdd(&num[dl0][ch0], w0 * bflo(f0));
        atomicAdd(&num[dl0][ch1], w0 * bfhi(f0));
        atomicAdd(&num[dl1][ch0], w1 * bflo(f1));
        atomicAdd(&num[dl1][ch1], w1 * bfhi(f1));
        atomicAdd(&num[dl2][ch0], w2 * bflo(f2));
        atomicAdd(&num[dl2][ch1], w2 * bfhi(f2));
        atomicAdd(&num[dl3][ch0], w3 * bflo(f3));
        atomicAdd(&num[dl3][ch1], w3 * bfhi(f3));
        if ((c & 7) == 0) {
            atomicAdd(&den[dl0][h], w0);
            atomicAdd(&den[dl1][h], w1);
            atomicAdd(&den[dl2][h], w2);
            atomicAdd(&den[dl3][h], w3);
        }
    }
    // tail: < 8 leftover edges, wave 0 only
    {
        int tb = start + ((end - start) & ~7);
        if (wid == 0) {
            for (int ee = tb + half; ee < end; ee += 2) {
                unsigned int pk = sorted_pk[ee];
                int s = (int)(pk >> 7);
                int dl = (int)(pk & 127u);
                float wv = __expf(lrelu(el[(size_t)s * 4 + h] + er_s[dl * 4 + h]));
                unsigned int f = *(const unsigned int*)(fsb + (size_t)s * O_OUT + 2 * c);
                atomicAdd(&num[dl][ch0], wv * bflo(f));
                atomicAdd(&num[dl][ch1], wv * bfhi(f));
                if ((c & 7) == 0) atomicAdd(&den[dl][h], wv);
            }
        }
    }
    __syncthreads();

    // epilogue: out[node] += num/den (out already holds resval from proj)
#pragma unroll
    for (int i = 0; i < 4; ++i) {
        int idx = i * 2048 + t * 4;        // 0..8188, step 4
        int row = idx >> 6;
        int ch = idx & 63;                 // multiple of 4, h-group uniform
        int node = r * 128 + row;
        if (node < N) {
            float inv = 1.0f / fmaxf(den[row][ch >> 4], 1e-20f);
            float4 v = *(const float4*)(&num[row][ch]);
            float4* po = (float4*)(out + (size_t)node * O_OUT + ch);
            float4 o = *po;
            o.x += v.x * inv; o.y += v.y * inv;
            o.z += v.z * inv; o.w += v.w * inv;
            *po = o;
        }
    }
}

// ---------------------------------------------------------------------------
// Fallback path (small ws): no-max softmax, atomics, bf16 fs.
// ---------------------------------------------------------------------------
__global__ __launch_bounds__(256) void edge_sum_kernel(
    const int* __restrict__ src, const int* __restrict__ dst,
    const float* __restrict__ el, const float* __restrict__ er,
    float* __restrict__ denom, int E)
{
    int e = blockIdx.x * 256 + threadIdx.x;
    if (e >= E) return;
    int s = src[e], d = dst[e];
    float4 l4 = ((const float4*)el)[s];
    float4 r4 = ((const float4*)er)[d];
    unsafeAtomicAdd(&denom[(size_t)d * 4 + 0], __expf(lrelu(l4.x + r4.x)));
    unsafeAtomicAdd(&denom[(size_t)d * 4 + 1], __expf(lrelu(l4.y + r4.y)));
    unsafeAtomicAdd(&denom[(size_t)d * 4 + 2], __expf(lrelu(l4.z + r4.z)));
    unsafeAtomicAdd(&denom[(size_t)d * 4 + 3], __expf(lrelu(l4.w + r4.w)));
}

__global__ __launch_bounds__(256) void agg_atomic_kernel(
    const int* __restrict__ src, const int* __restrict__ dst,
    const unsigned short* __restrict__ fsb, const float* __restrict__ el,
    const float* __restrict__ er, const float* __restrict__ denom,
    float* __restrict__ out, int E)
{
    const int lane = threadIdx.x & 63;
    const int wid = threadIdx.x >> 6;
    int e = blockIdx.x * 4 + wid;
    if (e >= E) return;
    int s = src[e], d = dst[e];
    // invert head-aligned pair swizzle: position `lane` -> channel ch
    int h = lane >> 4;                 // head of this position
    int jj = (lane >> 1) & 7;
    int hi2 = (lane >> 5) & 1;
    int odd = lane & 1;
    int ch = 16 * h + jj + 8 * (hi2 ^ odd);
    float v = __expf(lrelu(el[(size_t)s * 4 + h] + er[(size_t)d * 4 + h]));
    float alpha = v / fmaxf(denom[(size_t)d * 4 + h], 1e-20f);
    float fval = __uint_as_float(((unsigned int)fsb[(size_t)s * O_OUT + lane]) << 16);
    unsafeAtomicAdd(&out[(size_t)d * O_OUT + ch], alpha * fval);
}

extern "C" void kernel_launch(void* const* d_in, const int* in_sizes, int n_in,
                              void* d_out, int out_size, void* d_ws, size_t ws_size,
                              hipStream_t stream) {
    const float* feat   = (const float*)d_in[0];
    const float* Wfc    = (const float*)d_in[1];
    const float* attn_l = (const float*)d_in[2];
    const float* attn_r = (const float*)d_in[3];
    const float* Wres   = (const float*)d_in[4];
    const int*   src    = (const int*)d_in[5];
    const int*   dst    = (const int*)d_in[6];

    const int N = in_sizes[0] / F_IN;     // 100000
    const int E = in_sizes[5];            // 3200000
    float* out = (float*)d_out;

    const int R = (N + 127) >> 7;                 // buckets of 128 nodes
    const int B = (E + CHUNK - 1) / CHUNK;        // blocks in bucket passes
    const int nRB = R * B;
    const int nsb = (nRB + 1023) / 1024;

    // layout: el | er | Bf | histT[nRB] | histS[nRB+8] | bsums[1024] |
    //         sorted_pk[E] | fsb
    float* el     = (float*)d_ws;
    float* er     = el + (size_t)N * 4;
    unsigned short* Bf = (unsigned short*)(er + (size_t)N * 4);
    int*   histT  = (int*)(Bf + 32768);
    int*   histS  = histT + nRB;
    int*   bsums  = histS + nRB + 8;
    unsigned int* sorted_pk = (unsigned int*)(bsums + 1024);
    unsigned short* fsb = (unsigned short*)(sorted_pk + E);
    size_t need_main = (size_t)((char*)(fsb + (size_t)N * O_OUT) - (char*)d_ws);

    int nproj = (N + 63) / 64;

    if (ws_size >= need_main && R <= RMAX && nsb <= 1024) {
        wprep_kernel<<<16, 256, 0, stream>>>(Wfc, Wres, Bf);
        proj_mfma_kernel<<<nproj, 256, 0, stream>>>(
            feat, Bf, attn_l, attn_r, fsb, el, er, out, nullptr, N);
        bucket_count_kernel<<<B, 256, 0, stream>>>(dst, histT, E, B, R);
        scan_block_kernel<<<nsb, 256, 0, stream>>>(histT, histS, bsums, nRB);
        scan_bsums_kernel<<<1, 64, 0, stream>>>(bsums, nsb);
        scan_final_kernel<<<(nRB + 255) / 256, 256, 0, stream>>>(histS, bsums, nRB, E);
        bucket_scatter_kernel<<<B, 256, 0, stream>>>(src, dst, histS, sorted_pk, E, B, R);
        agg_fused_kernel<<<R, 512, 0, stream>>>(
            histS, sorted_pk, fsb, el, er, out, N, E, B, R);
    } else {
        // fallback: denom overlays histT region; fsb right after denom
        float* denom = (float*)histT;                 // [N*4]
        unsigned short* fsb2 = (unsigned short*)(denom + (size_t)N * 4);
        wprep_kernel<<<16, 256, 0, stream>>>(Wfc, Wres, Bf);
        proj_mfma_kernel<<<nproj, 256, 0, stream>>>(
            feat, Bf, attn_l, attn_r, fsb2, el, er, out, denom, N);
        edge_sum_kernel<<<(E + 255) / 256, 256, 0, stream>>>(src, dst, el, er, denom, E);
        agg_atomic_kernel<<<(E + 3) / 4, 256, 0, stream>>>(
            src, dst, fsb2, el, er, denom, out, E);
    }
}

// Round 5
// 1719.355 us; speedup vs baseline: 1.0020x; 1.0009x over previous
//
#include <hip/hip_runtime.h>
#include <hip/hip_bf16.h>

// GAT, H=4 heads x D=16, O=64 out channels, F=256 in features.
// Pipeline: wprep (W -> bf16 MFMA B-frags) -> proj_mfma (bf16 MFMA GEMM,
// fc -> fsb bf16 (head-aligned pair swizzle) + el/er logits, res -> out fp32)
// -> bucket_count (LDS hist over dst>>7) -> scan(3) over histT ->
// bucket_scatter (LDS-rank, packed (src<<7|dstlow) runs) ->
// agg_fused (per-bucket LDS fp32 accumulators fed by unsafeAtomicAdd, which
//            emits hardware ds_add_f32 -- plain atomicAdd(float) on LDS was
//            lowered to a CAS retry loop (rounds 2-3: 1450us, all pipes
//            idle), serializing the LDS pipe).
// NO global atomics anywhere in the main path.
// Softmax max-subtraction omitted: scores O(1), exp safe in fp32,
// softmax shift-invariant -> identical result.
//
// fsb swizzle (head-aligned): agg lane c (h=c>>3, j=c&7, hi2=h>>1) owns
//   ch0 = 16h + j + 8*hi2     (low  ushort of its dword, pos 2c)
//   ch1 = 16h + j + 8*(1-hi2) (high ushort, pos 2c+1)
// Both channels in head h -> ONE exp weight per lane is correct.
// ch0 % 32 and ch1 % 32 are each bijections over the half-wave ->
// both LDS adds conflict-free per half (2-way per wave = free).

#define F_IN 256
#define O_OUT 64
#define NEG_SLOPE 0.2f
#define CHUNK 4096           // edges per block in bucket passes (782 blocks)
#define RMAX 2048            // max buckets supported by LDS hist

using frag_ab = __attribute__((ext_vector_type(8))) short;   // 8 bf16
using frag_cd = __attribute__((ext_vector_type(4))) float;   // 4 fp32

__device__ __forceinline__ float lrelu(float x) {
    return x >= 0.0f ? x : NEG_SLOPE * x;
}

__device__ __forceinline__ unsigned short f2bf(float f) {
    unsigned int u = __float_as_uint(f);
    unsigned int r = (u + 0x7fffu + ((u >> 16) & 1u)) >> 16;   // RNE
    return (unsigned short)r;
}
__device__ __forceinline__ float bflo(unsigned int p) {
    return __uint_as_float(p << 16);
}
__device__ __forceinline__ float bfhi(unsigned int p) {
    return __uint_as_float(p & 0xffff0000u);
}

// fsb position of channel ch under the head-aligned pair swizzle.
__device__ __forceinline__ int fsb_pos(int ch) {
    int h = ch >> 4;
    int jp = ch & 15;          // within-head index
    int hi2 = h >> 1;
    int jj = jp & 7;
    int c_lane = 8 * h + jj;
    // is_ch0: hi2==0 -> jp<8 ; hi2==1 -> jp>=8
    int is_ch0 = (hi2 == 0) ? (jp < 8) : (jp >= 8);
    return 2 * c_lane + (is_ch0 ? 0 : 1);
}

// ---------------------------------------------------------------------------
// Weight prep: Wfc/Wres fp32 [64][256] -> Bf bf16 in MFMA B-frag lane order.
// ---------------------------------------------------------------------------
__global__ __launch_bounds__(256) void wprep_kernel(
    const float* __restrict__ Wfc, const float* __restrict__ Wres,
    unsigned short* __restrict__ Bf)
{
    int tid = blockIdx.x * 256 + threadIdx.x;   // 0..4095
    int ct = tid >> 9;
    int lane = tid & 63;
    int ks = (tid >> 6) & 7;
    int col = ct * 16 + (lane & 15);
    int kbase = ks * 32 + (lane >> 4) * 8;
    const float* srcW = (col < 64) ? (Wfc + (size_t)col * 256 + kbase)
                                   : (Wres + (size_t)(col - 64) * 256 + kbase);
    unsigned short* dstp = Bf + (size_t)tid * 8;
#pragma unroll
    for (int i = 0; i < 8; ++i) dstp[i] = f2bf(srcW[i]);
}

// ---------------------------------------------------------------------------
// MFMA projection: block = 256 threads (4 waves), 64 nodes.
// ---------------------------------------------------------------------------
__global__ __launch_bounds__(256) void proj_mfma_kernel(
    const float* __restrict__ feat, const unsigned short* __restrict__ Bf,
    const float* __restrict__ attn_l, const float* __restrict__ attn_r,
    unsigned short* __restrict__ fsb, float* __restrict__ el,
    float* __restrict__ er, float* __restrict__ out,
    float* __restrict__ denom_zero, int N)
{
    __shared__ __align__(16) unsigned short sA[64 * 280];   // 35840 B
    const int t = threadIdx.x;
    const int lane = t & 63;
    const int w = t >> 6;
    const int n0 = blockIdx.x * 64;
    if (n0 >= N) return;

    frag_ab bfrag[2][8];
    {
        const unsigned short* bp = Bf + (size_t)lane * 8;
#pragma unroll
        for (int j = 0; j < 2; ++j)
#pragma unroll
            for (int ks = 0; ks < 8; ++ks)
                bfrag[j][ks] = *(const frag_ab*)(bp + (size_t)((2 * w + j) * 8 + ks) * 512);
    }

    if (denom_zero && n0 * 4 + t < N * 4) denom_zero[n0 * 4 + t] = 0.0f;

    for (int i = 0; i < 8; ++i) {
        int f = i * 256 + t;
        int row = f >> 5, c8 = f & 31;
        int n = n0 + row;
        float4 v0 = make_float4(0.f, 0.f, 0.f, 0.f), v1 = v0;
        if (n < N) {
            const float4* p = (const float4*)(feat + (size_t)n * F_IN + c8 * 8);
            v0 = p[0]; v1 = p[1];
        }
        frag_ab pack;
        pack[0] = (short)f2bf(v0.x); pack[1] = (short)f2bf(v0.y);
        pack[2] = (short)f2bf(v0.z); pack[3] = (short)f2bf(v0.w);
        pack[4] = (short)f2bf(v1.x); pack[5] = (short)f2bf(v1.y);
        pack[6] = (short)f2bf(v1.z); pack[7] = (short)f2bf(v1.w);
        *(frag_ab*)(&sA[row * 280 + c8 * 8]) = pack;
    }
    __syncthreads();

    frag_cd acc[4][2];
#pragma unroll
    for (int rt = 0; rt < 4; ++rt)
#pragma unroll
        for (int j = 0; j < 2; ++j)
            acc[rt][j] = (frag_cd){0.f, 0.f, 0.f, 0.f};

#pragma unroll
    for (int ks = 0; ks < 8; ++ks) {
        frag_ab af[4];
#pragma unroll
        for (int rt = 0; rt < 4; ++rt) {
            int row = rt * 16 + (lane & 15);
            int c8 = ks * 4 + (lane >> 4);
            af[rt] = *(const frag_ab*)(&sA[row * 280 + c8 * 8]);
        }
#pragma unroll
        for (int rt = 0; rt < 4; ++rt)
#pragma unroll
            for (int j = 0; j < 2; ++j)
                acc[rt][j] = __builtin_amdgcn_mfma_f32_16x16x32_bf16(
                    af[rt], bfrag[j][ks], acc[rt][j], 0, 0, 0);
    }

    // epilogue: C/D layout col = lane&15, row = (lane>>4)*4 + reg  [m89]
    const int colq = lane & 15;
    const int quad = lane >> 4;
    if (w < 2) {
#pragma unroll
        for (int j = 0; j < 2; ++j) {
            int h = 2 * w + j;
            float al = attn_l[h * 16 + colq];
            float ar = attn_r[h * 16 + colq];
            int pos = fsb_pos(h * 16 + colq);    // head-aligned pair swizzle
#pragma unroll
            for (int rt = 0; rt < 4; ++rt)
#pragma unroll
                for (int r = 0; r < 4; ++r) {
                    int node = n0 + rt * 16 + quad * 4 + r;
                    float v = acc[rt][j][r];
                    if (node < N) fsb[(size_t)node * O_OUT + pos] = f2bf(v);
                    float pl = v * al, pr = v * ar;
                    pl += __shfl_xor(pl, 1); pr += __shfl_xor(pr, 1);
                    pl += __shfl_xor(pl, 2); pr += __shfl_xor(pr, 2);
                    pl += __shfl_xor(pl, 4); pr += __shfl_xor(pr, 4);
                    pl += __shfl_xor(pl, 8); pr += __shfl_xor(pr, 8);
                    if (colq == 0 && node < N) {
                        el[(size_t)node * 4 + h] = pl;
                        er[(size_t)node * 4 + h] = pr;
                    }
                }
        }
    } else {
#pragma unroll
        for (int j = 0; j < 2; ++j) {
            int cb = 32 * (w - 2) + 16 * j;
#pragma unroll
            for (int rt = 0; rt < 4; ++rt)
#pragma unroll
                for (int r = 0; r < 4; ++r) {
                    int node = n0 + rt * 16 + quad * 4 + r;
                    if (node < N)
                        out[(size_t)node * O_OUT + cb + colq] = acc[rt][j][r];
                }
        }
    }
}

// ---------------------------------------------------------------------------
// Bucket pass A: per-block LDS histogram of dst>>7 -> histT[bin*B + b].
// ---------------------------------------------------------------------------
__global__ __launch_bounds__(256) void bucket_count_kernel(
    const int* __restrict__ dst, int* __restrict__ histT, int E, int B, int R)
{
    __shared__ int h[RMAX];
    int b = blockIdx.x, t = threadIdx.x;
    for (int i = t; i < R; i += 256) h[i] = 0;
    __syncthreads();
    int base = b * CHUNK;
    for (int i = t; i < CHUNK; i += 256) {
        int e = base + i;
        if (e < E) atomicAdd(&h[dst[e] >> 7], 1);
    }
    __syncthreads();
    for (int i = t; i < R; i += 256) histT[(size_t)i * B + b] = h[i];
}

// ---------------------------------------------------------------------------
// Scan chain (exclusive prefix sum over arbitrary n, 1024/block).
// ---------------------------------------------------------------------------
__global__ __launch_bounds__(256) void scan_block_kernel(
    const int* __restrict__ counts, int* __restrict__ outp,
    int* __restrict__ bsums, int n)
{
    int t = threadIdx.x;
    int base = blockIdx.x * 1024 + t * 4;
    int c0 = 0, c1 = 0, c2 = 0, c3 = 0;
    if (base + 3 < n) {
        int4 v = *(const int4*)(counts + base);
        c0 = v.x; c1 = v.y; c2 = v.z; c3 = v.w;
    } else {
        if (base     < n) c0 = counts[base];
        if (base + 1 < n) c1 = counts[base + 1];
        if (base + 2 < n) c2 = counts[base + 2];
        if (base + 3 < n) c3 = counts[base + 3];
    }
    int tsum = c0 + c1 + c2 + c3;
    int inc = tsum;
    int lane = t & 63, wid = t >> 6;
#pragma unroll
    for (int o = 1; o < 64; o <<= 1) {
        int v = __shfl_up(inc, o);
        if (lane >= o) inc += v;
    }
    __shared__ int wsum[4];
    if (lane == 63) wsum[wid] = inc;
    __syncthreads();
    int woff = 0;
#pragma unroll
    for (int w = 0; w < 4; ++w)
        if (w < wid) woff += wsum[w];
    int excl = woff + inc - tsum;
    int e0 = excl, e1 = excl + c0, e2 = e1 + c1, e3 = e2 + c2;
    if (base + 3 < n) {
        *(int4*)(outp + base) = make_int4(e0, e1, e2, e3);
    } else {
        if (base     < n) outp[base]     = e0;
        if (base + 1 < n) outp[base + 1] = e1;
        if (base + 2 < n) outp[base + 2] = e2;
        if (base + 3 < n) outp[base + 3] = e3;
    }
    if (t == 255) bsums[blockIdx.x] = wsum[0] + wsum[1] + wsum[2] + wsum[3];
}

__global__ void scan_bsums_kernel(int* __restrict__ bsums, int nb)
{
    int lane = threadIdx.x;   // 64 threads
    int carry = 0;
    for (int c = 0; c * 64 < nb; ++c) {
        int i = c * 64 + lane;
        int v = (i < nb) ? bsums[i] : 0;
        int inc = v;
#pragma unroll
        for (int o = 1; o < 64; o <<= 1) {
            int u = __shfl_up(inc, o);
            if (lane >= o) inc += u;
        }
        if (i < nb) bsums[i] = carry + inc - v;
        carry += __shfl(inc, 63);
    }
}

__global__ __launch_bounds__(256) void scan_final_kernel(
    int* __restrict__ outp, const int* __restrict__ bsums, int n, int total)
{
    int i = blockIdx.x * 256 + threadIdx.x;
    if (i < n) outp[i] = outp[i] + bsums[i >> 10];
    if (i == 0) outp[n] = total;   // outp must have n+1 capacity
}

// ---------------------------------------------------------------------------
// Bucket pass C: LDS-atomic local rank; write packed (src<<7)|dstlow to
// sorted_pk at histS[bin*B+b] + rank. Per-bucket runs are contiguous.
// ---------------------------------------------------------------------------
__global__ __launch_bounds__(256) void bucket_scatter_kernel(
    const int* __restrict__ src, const int* __restrict__ dst,
    const int* __restrict__ histS, unsigned int* __restrict__ sorted_pk,
    int E, int B, int R)
{
    __shared__ int h[RMAX];
    __shared__ int basebin[RMAX];
    int b = blockIdx.x, t = threadIdx.x;
    for (int i = t; i < R; i += 256) {
        h[i] = 0;
        basebin[i] = histS[(size_t)i * B + b];
    }
    __syncthreads();
    int base = b * CHUNK;
    for (int i = t; i < CHUNK; i += 256) {
        int e = base + i;
        if (e < E) {
            int d = dst[e];
            int bin = d >> 7;
            int rk = atomicAdd(&h[bin], 1);
            sorted_pk[basebin[bin] + rk] =
                ((unsigned int)src[e] << 7) | (unsigned int)(d & 127);
        }
    }
}

// ---------------------------------------------------------------------------
// Fused aggregation: one block per bucket (128 dst nodes), 512 threads.
// LDS fp32 accumulators (num[128][64] + den[128][4]) fed by unsafeAtomicAdd
// (hardware ds_add_f32); consumes sorted_pk runs directly.
// Each half-wave owns one edge; lane c owns head-aligned channel pair.
// ---------------------------------------------------------------------------
__global__ __launch_bounds__(512) void agg_fused_kernel(
    const int* __restrict__ histS, const unsigned int* __restrict__ sorted_pk,
    const unsigned short* __restrict__ fsb, const float* __restrict__ el,
    const float* __restrict__ er, float* __restrict__ out,
    int N, int E, int B, int R)
{
    __shared__ float num[128][64];    // 32 KiB
    __shared__ float den[128][4];     // 2 KiB
    __shared__ float er_s[512];       // 2 KiB
    const int r = blockIdx.x;
    const int t = threadIdx.x;

    float* np = &num[0][0];
    for (int i = t; i < 128 * 64; i += 512) np[i] = 0.f;
    ((float*)den)[t] = 0.f;                       // 512 floats exactly
    int gn = r * 512 + t;
    er_s[t] = (gn < N * 4) ? er[gn] : 0.f;
    __syncthreads();

    const int start = histS[(size_t)r * B];
    const int end = (r + 1 < R) ? histS[(size_t)(r + 1) * B] : E;
    const int lane = t & 63;
    const int wid = t >> 6;            // 0..7
    const int half = lane >> 5;
    const int c = lane & 31;
    const int h = c >> 3;
    const int hi2 = h >> 1;
    const int ch0 = 16 * h + (c & 7) + 8 * hi2;        // bijective mod 32
    const int ch1 = 16 * h + (c & 7) + 8 * (1 - hi2);  // bijective mod 32
    const bool do_den = ((c & 7) == 0);

    // main loop: 8 edges (4 pairs) per wave iteration; phase-split loads.
    int kb = start + wid * 8;
    for (; kb + 8 <= end; kb += 8 * 8) {
        unsigned int pk0 = sorted_pk[kb + 0 + half];
        unsigned int pk1 = sorted_pk[kb + 2 + half];
        unsigned int pk2 = sorted_pk[kb + 4 + half];
        unsigned int pk3 = sorted_pk[kb + 6 + half];
        int s0 = (int)(pk0 >> 7), dl0 = (int)(pk0 & 127u);
        int s1 = (int)(pk1 >> 7), dl1 = (int)(pk1 & 127u);
        int s2 = (int)(pk2 >> 7), dl2 = (int)(pk2 & 127u);
        int s3 = (int)(pk3 >> 7), dl3 = (int)(pk3 & 127u);
        float ea0 = el[(size_t)s0 * 4 + h];
        float ea1 = el[(size_t)s1 * 4 + h];
        float ea2 = el[(size_t)s2 * 4 + h];
        float ea3 = el[(size_t)s3 * 4 + h];
        unsigned int f0 = *(const unsigned int*)(fsb + (size_t)s0 * O_OUT + 2 * c);
        unsigned int f1 = *(const unsigned int*)(fsb + (size_t)s1 * O_OUT + 2 * c);
        unsigned int f2 = *(const unsigned int*)(fsb + (size_t)s2 * O_OUT + 2 * c);
        unsigned int f3 = *(const unsigned int*)(fsb + (size_t)s3 * O_OUT + 2 * c);
        float w0 = __expf(lrelu(ea0 + er_s[dl0 * 4 + h]));
        float w1 = __expf(lrelu(ea1 + er_s[dl1 * 4 + h]));
        float w2 = __expf(lrelu(ea2 + er_s[dl2 * 4 + h]));
        float w3 = __expf(lrelu(ea3 + er_s[dl3 * 4 + h]));
        unsafeAtomicAdd(&num[dl0][ch0], w0 * bflo(f0));
        unsafeAtomicAdd(&num[dl0][ch1], w0 * bfhi(f0));
        unsafeAtomicAdd(&num[dl1][ch0], w1 * bflo(f1));
        unsafeAtomicAdd(&num[dl1][ch1], w1 * bfhi(f1));
        unsafeAtomicAdd(&num[dl2][ch0], w2 * bflo(f2));
        unsafeAtomicAdd(&num[dl2][ch1], w2 * bfhi(f2));
        unsafeAtomicAdd(&num[dl3][ch0], w3 * bflo(f3));
        unsafeAtomicAdd(&num[dl3][ch1], w3 * bfhi(f3));
        if (do_den) {
            unsafeAtomicAdd(&den[dl0][h], w0);
            unsafeAtomicAdd(&den[dl1][h], w1);
            unsafeAtomicAdd(&den[dl2][h], w2);
            unsafeAtomicAdd(&den[dl3][h], w3);
        }
    }
    // tail: < 8 leftover edges, wave 0 only
    {
        int tb = start + ((end - start) & ~7);
        if (wid == 0) {
            for (int ee = tb + half; ee < end; ee += 2) {
                unsigned int pk = sorted_pk[ee];
                int s = (int)(pk >> 7);
                int dl = (int)(pk & 127u);
                float wv = __expf(lrelu(el[(size_t)s * 4 + h] + er_s[dl * 4 + h]));
                unsigned int f = *(const unsigned int*)(fsb + (size_t)s * O_OUT + 2 * c);
                unsafeAtomicAdd(&num[dl][ch0], wv * bflo(f));
                unsafeAtomicAdd(&num[dl][ch1], wv * bfhi(f));
                if (do_den) unsafeAtomicAdd(&den[dl][h], wv);
            }
        }
    }
    __syncthreads();

    // epilogue: out[node] += num/den (out already holds resval from proj)
#pragma unroll
    for (int i = 0; i < 4; ++i) {
        int idx = i * 2048 + t * 4;        // 0..8188, step 4
        int row = idx >> 6;
        int ch = idx & 63;                 // multiple of 4, h-group uniform
        int node = r * 128 + row;
        if (node < N) {
            float inv = 1.0f / fmaxf(den[row][ch >> 4], 1e-20f);
            float4 v = *(const float4*)(&num[row][ch]);
            float4* po = (float4*)(out + (size_t)node * O_OUT + ch);
            float4 o = *po;
            o.x += v.x * inv; o.y += v.y * inv;
            o.z += v.z * inv; o.w += v.w * inv;
            *po = o;
        }
    }
}

// ---------------------------------------------------------------------------
// Fallback path (small ws): no-max softmax, atomics, bf16 fs.
// ---------------------------------------------------------------------------
__global__ __launch_bounds__(256) void edge_sum_kernel(
    const int* __restrict__ src, const int* __restrict__ dst,
    const float* __restrict__ el, const float* __restrict__ er,
    float* __restrict__ denom, int E)
{
    int e = blockIdx.x * 256 + threadIdx.x;
    if (e >= E) return;
    int s = src[e], d = dst[e];
    float4 l4 = ((const float4*)el)[s];
    float4 r4 = ((const float4*)er)[d];
    unsafeAtomicAdd(&denom[(size_t)d * 4 + 0], __expf(lrelu(l4.x + r4.x)));
    unsafeAtomicAdd(&denom[(size_t)d * 4 + 1], __expf(lrelu(l4.y + r4.y)));
    unsafeAtomicAdd(&denom[(size_t)d * 4 + 2], __expf(lrelu(l4.z + r4.z)));
    unsafeAtomicAdd(&denom[(size_t)d * 4 + 3], __expf(lrelu(l4.w + r4.w)));
}

__global__ __launch_bounds__(256) void agg_atomic_kernel(
    const int* __restrict__ src, const int* __restrict__ dst,
    const unsigned short* __restrict__ fsb, const float* __restrict__ el,
    const float* __restrict__ er, const float* __restrict__ denom,
    float* __restrict__ out, int E)
{
    const int lane = threadIdx.x & 63;
    const int wid = threadIdx.x >> 6;
    int e = blockIdx.x * 4 + wid;
    if (e >= E) return;
    int s = src[e], d = dst[e];
    // invert head-aligned pair swizzle: position `lane` -> channel ch
    int h = lane >> 4;                 // head of this position
    int jj = (lane >> 1) & 7;
    int hi2 = (lane >> 5) & 1;
    int odd = lane & 1;
    int ch = 16 * h + jj + 8 * (hi2 ^ odd);
    float v = __expf(lrelu(el[(size_t)s * 4 + h] + er[(size_t)d * 4 + h]));
    float alpha = v / fmaxf(denom[(size_t)d * 4 + h], 1e-20f);
    float fval = __uint_as_float(((unsigned int)fsb[(size_t)s * O_OUT + lane]) << 16);
    unsafeAtomicAdd(&out[(size_t)d * O_OUT + ch], alpha * fval);
}

extern "C" void kernel_launch(void* const* d_in, const int* in_sizes, int n_in,
                              void* d_out, int out_size, void* d_ws, size_t ws_size,
                              hipStream_t stream) {
    const float* feat   = (const float*)d_in[0];
    const float* Wfc    = (const float*)d_in[1];
    const float* attn_l = (const float*)d_in[2];
    const float* attn_r = (const float*)d_in[3];
    const float* Wres   = (const float*)d_in[4];
    const int*   src    = (const int*)d_in[5];
    const int*   dst    = (const int*)d_in[6];

    const int N = in_sizes[0] / F_IN;     // 100000
    const int E = in_sizes[5];            // 3200000
    float* out = (float*)d_out;

    const int R = (N + 127) >> 7;                 // buckets of 128 nodes
    const int B = (E + CHUNK - 1) / CHUNK;        // blocks in bucket passes
    const int nRB = R * B;
    const int nsb = (nRB + 1023) / 1024;

    // layout: el | er | Bf | histT[nRB] | histS[nRB+8] | bsums[1024] |
    //         sorted_pk[E] | fsb
    float* el     = (float*)d_ws;
    float* er     = el + (size_t)N * 4;
    unsigned short* Bf = (unsigned short*)(er + (size_t)N * 4);
    int*   histT  = (int*)(Bf + 32768);
    int*   histS  = histT + nRB;
    int*   bsums  = histS + nRB + 8;
    unsigned int* sorted_pk = (unsigned int*)(bsums + 1024);
    unsigned short* fsb = (unsigned short*)(sorted_pk + E);
    size_t need_main = (size_t)((char*)(fsb + (size_t)N * O_OUT) - (char*)d_ws);

    int nproj = (N + 63) / 64;

    if (ws_size >= need_main && R <= RMAX && nsb <= 1024) {
        wprep_kernel<<<16, 256, 0, stream>>>(Wfc, Wres, Bf);
        proj_mfma_kernel<<<nproj, 256, 0, stream>>>(
            feat, Bf, attn_l, attn_r, fsb, el, er, out, nullptr, N);
        bucket_count_kernel<<<B, 256, 0, stream>>>(dst, histT, E, B, R);
        scan_block_kernel<<<nsb, 256, 0, stream>>>(histT, histS, bsums, nRB);
        scan_bsums_kernel<<<1, 64, 0, stream>>>(bsums, nsb);
        scan_final_kernel<<<(nRB + 255) / 256, 256, 0, stream>>>(histS, bsums, nRB, E);
        bucket_scatter_kernel<<<B, 256, 0, stream>>>(src, dst, histS, sorted_pk, E, B, R);
        agg_fused_kernel<<<R, 512, 0, stream>>>(
            histS, sorted_pk, fsb, el, er, out, N, E, B, R);
    } else {
        // fallback: denom overlays histT region; fsb right after denom
        float* denom = (float*)histT;                 // [N*4]
        unsigned short* fsb2 = (unsigned short*)(denom + (size_t)N * 4);
        wprep_kernel<<<16, 256, 0, stream>>>(Wfc, Wres, Bf);
        proj_mfma_kernel<<<nproj, 256, 0, stream>>>(
            feat, Bf, attn_l, attn_r, fsb2, el, er, out, denom, N);
        edge_sum_kernel<<<(E + 255) / 256, 256, 0, stream>>>(src, dst, el, er, denom, E);
        agg_atomic_kernel<<<(E + 3) / 4, 256, 0, stream>>>(
            src, dst, fsb2, el, er, denom, out, E);
    }
}

// Round 6
// 597.360 us; speedup vs baseline: 2.8841x; 2.8783x over previous
//
#include <hip/hip_runtime.h>
#include <hip/hip_bf16.h>

// GAT, H=4 heads x D=16, O=64 out channels, F=256 in features.
// Pipeline: wprep (W -> bf16 MFMA B-frags) -> proj_mfma (bf16 MFMA GEMM,
// fc -> fsb bf16 + el/er logits, res -> out fp32) ->
// CSR build via global int atomics:
//   zero(count) -> hist (atomicAdd count[dst]) -> scan(3) -> rowptr ->
//   scatter (atomicSub count[d] -> slot; sorted_src[rowptr[d]+old-1]=src)
// -> agg_csr (pull-mode, one wave per dst, no fp atomics).
// LDS fp32-atomic aggregation (rounds 2-5) abandoned: 3 variants all at
// 1450us with identical counters -- the design serializes; agg_csr does the
// same gather volume in 119us. Int atomics here are native & L2-resident.
// Softmax max-subtraction omitted: scores O(1), exp safe in fp32,
// softmax shift-invariant -> identical result.

#define F_IN 256
#define O_OUT 64
#define NEG_SLOPE 0.2f

using frag_ab = __attribute__((ext_vector_type(8))) short;   // 8 bf16
using frag_cd = __attribute__((ext_vector_type(4))) float;   // 4 fp32

__device__ __forceinline__ float lrelu(float x) {
    return x >= 0.0f ? x : NEG_SLOPE * x;
}

__device__ __forceinline__ unsigned short f2bf(float f) {
    unsigned int u = __float_as_uint(f);
    unsigned int r = (u + 0x7fffu + ((u >> 16) & 1u)) >> 16;   // RNE
    return (unsigned short)r;
}
__device__ __forceinline__ float bflo(unsigned int p) {
    return __uint_as_float(p << 16);
}
__device__ __forceinline__ float bfhi(unsigned int p) {
    return __uint_as_float(p & 0xffff0000u);
}

// ---------------------------------------------------------------------------
// Weight prep: Wfc/Wres fp32 [64][256] -> Bf bf16 in MFMA B-frag lane order.
// ---------------------------------------------------------------------------
__global__ __launch_bounds__(256) void wprep_kernel(
    const float* __restrict__ Wfc, const float* __restrict__ Wres,
    unsigned short* __restrict__ Bf)
{
    int tid = blockIdx.x * 256 + threadIdx.x;   // 0..4095
    int ct = tid >> 9;
    int lane = tid & 63;
    int ks = (tid >> 6) & 7;
    int col = ct * 16 + (lane & 15);
    int kbase = ks * 32 + (lane >> 4) * 8;
    const float* srcW = (col < 64) ? (Wfc + (size_t)col * 256 + kbase)
                                   : (Wres + (size_t)(col - 64) * 256 + kbase);
    unsigned short* dstp = Bf + (size_t)tid * 8;
#pragma unroll
    for (int i = 0; i < 8; ++i) dstp[i] = f2bf(srcW[i]);
}

// ---------------------------------------------------------------------------
// MFMA projection: block = 256 threads (4 waves), 64 nodes.
// ---------------------------------------------------------------------------
__global__ __launch_bounds__(256) void proj_mfma_kernel(
    const float* __restrict__ feat, const unsigned short* __restrict__ Bf,
    const float* __restrict__ attn_l, const float* __restrict__ attn_r,
    unsigned short* __restrict__ fsb, float* __restrict__ el,
    float* __restrict__ er, float* __restrict__ out,
    float* __restrict__ denom_zero, int N)
{
    __shared__ __align__(16) unsigned short sA[64 * 280];   // 35840 B
    const int t = threadIdx.x;
    const int lane = t & 63;
    const int w = t >> 6;
    const int n0 = blockIdx.x * 64;
    if (n0 >= N) return;

    frag_ab bfrag[2][8];
    {
        const unsigned short* bp = Bf + (size_t)lane * 8;
#pragma unroll
        for (int j = 0; j < 2; ++j)
#pragma unroll
            for (int ks = 0; ks < 8; ++ks)
                bfrag[j][ks] = *(const frag_ab*)(bp + (size_t)((2 * w + j) * 8 + ks) * 512);
    }

    if (denom_zero && n0 * 4 + t < N * 4) denom_zero[n0 * 4 + t] = 0.0f;

    for (int i = 0; i < 8; ++i) {
        int f = i * 256 + t;
        int row = f >> 5, c8 = f & 31;
        int n = n0 + row;
        float4 v0 = make_float4(0.f, 0.f, 0.f, 0.f), v1 = v0;
        if (n < N) {
            const float4* p = (const float4*)(feat + (size_t)n * F_IN + c8 * 8);
            v0 = p[0]; v1 = p[1];
        }
        frag_ab pack;
        pack[0] = (short)f2bf(v0.x); pack[1] = (short)f2bf(v0.y);
        pack[2] = (short)f2bf(v0.z); pack[3] = (short)f2bf(v0.w);
        pack[4] = (short)f2bf(v1.x); pack[5] = (short)f2bf(v1.y);
        pack[6] = (short)f2bf(v1.z); pack[7] = (short)f2bf(v1.w);
        *(frag_ab*)(&sA[row * 280 + c8 * 8]) = pack;
    }
    __syncthreads();

    frag_cd acc[4][2];
#pragma unroll
    for (int rt = 0; rt < 4; ++rt)
#pragma unroll
        for (int j = 0; j < 2; ++j)
            acc[rt][j] = (frag_cd){0.f, 0.f, 0.f, 0.f};

#pragma unroll
    for (int ks = 0; ks < 8; ++ks) {
        frag_ab af[4];
#pragma unroll
        for (int rt = 0; rt < 4; ++rt) {
            int row = rt * 16 + (lane & 15);
            int c8 = ks * 4 + (lane >> 4);
            af[rt] = *(const frag_ab*)(&sA[row * 280 + c8 * 8]);
        }
#pragma unroll
        for (int rt = 0; rt < 4; ++rt)
#pragma unroll
            for (int j = 0; j < 2; ++j)
                acc[rt][j] = __builtin_amdgcn_mfma_f32_16x16x32_bf16(
                    af[rt], bfrag[j][ks], acc[rt][j], 0, 0, 0);
    }

    // epilogue: C/D layout col = lane&15, row = (lane>>4)*4 + reg  [m89]
    const int colq = lane & 15;
    const int quad = lane >> 4;
    if (w < 2) {
#pragma unroll
        for (int j = 0; j < 2; ++j) {
            int h = 2 * w + j;
            float al = attn_l[h * 16 + colq];
            float ar = attn_r[h * 16 + colq];
#pragma unroll
            for (int rt = 0; rt < 4; ++rt)
#pragma unroll
                for (int r = 0; r < 4; ++r) {
                    int node = n0 + rt * 16 + quad * 4 + r;
                    float v = acc[rt][j][r];
                    if (node < N) fsb[(size_t)node * O_OUT + h * 16 + colq] = f2bf(v);
                    float pl = v * al, pr = v * ar;
                    pl += __shfl_xor(pl, 1); pr += __shfl_xor(pr, 1);
                    pl += __shfl_xor(pl, 2); pr += __shfl_xor(pr, 2);
                    pl += __shfl_xor(pl, 4); pr += __shfl_xor(pr, 4);
                    pl += __shfl_xor(pl, 8); pr += __shfl_xor(pr, 8);
                    if (colq == 0 && node < N) {
                        el[(size_t)node * 4 + h] = pl;
                        er[(size_t)node * 4 + h] = pr;
                    }
                }
        }
    } else {
#pragma unroll
        for (int j = 0; j < 2; ++j) {
            int cb = 32 * (w - 2) + 16 * j;
#pragma unroll
            for (int rt = 0; rt < 4; ++rt)
#pragma unroll
                for (int r = 0; r < 4; ++r) {
                    int node = n0 + rt * 16 + quad * 4 + r;
                    if (node < N)
                        out[(size_t)node * O_OUT + cb + colq] = acc[rt][j][r];
                }
        }
    }
}

// ---------------------------------------------------------------------------
// CSR build: zero -> hist -> scan -> scatter.
// ---------------------------------------------------------------------------
__global__ __launch_bounds__(256) void zero_kernel(int* __restrict__ p, int n)
{
    int i = blockIdx.x * 256 + threadIdx.x;
    if (i < n) p[i] = 0;
}

__global__ __launch_bounds__(256) void hist_kernel(
    const int* __restrict__ dst, int* __restrict__ count, int E)
{
    int e = blockIdx.x * 256 + threadIdx.x;
    if (e < E) atomicAdd(&count[dst[e]], 1);
}

__global__ __launch_bounds__(256) void scatter_csr_kernel(
    const int* __restrict__ src, const int* __restrict__ dst,
    const int* __restrict__ rowptr, int* __restrict__ count,
    int* __restrict__ sorted_src, int E)
{
    int e = blockIdx.x * 256 + threadIdx.x;
    if (e >= E) return;
    int d = dst[e];
    int old = atomicSub(&count[d], 1);          // old in [1..deg]
    sorted_src[rowptr[d] + old - 1] = src[e];
}

// ---------------------------------------------------------------------------
// Scan chain (exclusive prefix sum over arbitrary n, 1024/block).
// ---------------------------------------------------------------------------
__global__ __launch_bounds__(256) void scan_block_kernel(
    const int* __restrict__ counts, int* __restrict__ outp,
    int* __restrict__ bsums, int n)
{
    int t = threadIdx.x;
    int base = blockIdx.x * 1024 + t * 4;
    int c0 = 0, c1 = 0, c2 = 0, c3 = 0;
    if (base + 3 < n) {
        int4 v = *(const int4*)(counts + base);
        c0 = v.x; c1 = v.y; c2 = v.z; c3 = v.w;
    } else {
        if (base     < n) c0 = counts[base];
        if (base + 1 < n) c1 = counts[base + 1];
        if (base + 2 < n) c2 = counts[base + 2];
        if (base + 3 < n) c3 = counts[base + 3];
    }
    int tsum = c0 + c1 + c2 + c3;
    int inc = tsum;
    int lane = t & 63, wid = t >> 6;
#pragma unroll
    for (int o = 1; o < 64; o <<= 1) {
        int v = __shfl_up(inc, o);
        if (lane >= o) inc += v;
    }
    __shared__ int wsum[4];
    if (lane == 63) wsum[wid] = inc;
    __syncthreads();
    int woff = 0;
#pragma unroll
    for (int w = 0; w < 4; ++w)
        if (w < wid) woff += wsum[w];
    int excl = woff + inc - tsum;
    int e0 = excl, e1 = excl + c0, e2 = e1 + c1, e3 = e2 + c2;
    if (base + 3 < n) {
        *(int4*)(outp + base) = make_int4(e0, e1, e2, e3);
    } else {
        if (base     < n) outp[base]     = e0;
        if (base + 1 < n) outp[base + 1] = e1;
        if (base + 2 < n) outp[base + 2] = e2;
        if (base + 3 < n) outp[base + 3] = e3;
    }
    if (t == 255) bsums[blockIdx.x] = wsum[0] + wsum[1] + wsum[2] + wsum[3];
}

__global__ void scan_bsums_kernel(int* __restrict__ bsums, int nb)
{
    int lane = threadIdx.x;   // 64 threads
    int carry = 0;
    for (int c = 0; c * 64 < nb; ++c) {
        int i = c * 64 + lane;
        int v = (i < nb) ? bsums[i] : 0;
        int inc = v;
#pragma unroll
        for (int o = 1; o < 64; o <<= 1) {
            int u = __shfl_up(inc, o);
            if (lane >= o) inc += u;
        }
        if (i < nb) bsums[i] = carry + inc - v;
        carry += __shfl(inc, 63);
    }
}

__global__ __launch_bounds__(256) void scan_final_kernel(
    int* __restrict__ outp, const int* __restrict__ bsums, int n, int total)
{
    int i = blockIdx.x * 256 + threadIdx.x;
    if (i < n) outp[i] = outp[i] + bsums[i >> 10];
    if (i == 0) outp[n] = total;   // outp must have n+1 capacity
}

// ---------------------------------------------------------------------------
// CSR aggregation: one wave per dst node. 2 edges/iter (half-waves), each
// lane owns a bf16x2 channel pair; 4 pairs unrolled. (Verified round-0.)
// ---------------------------------------------------------------------------
__global__ __launch_bounds__(256) void agg_csr_kernel(
    const int* __restrict__ rowptr, const int* __restrict__ srt,
    const unsigned short* __restrict__ fsb, const float* __restrict__ el,
    const float* __restrict__ er, float* __restrict__ out, int N)
{
    int d = blockIdx.x * 4 + (threadIdx.x >> 6);
    if (d >= N) return;
    const int lane = threadIdx.x & 63;
    const int half = lane >> 5;
    const int c = lane & 31;           // channels 2c, 2c+1
    const int h = c >> 3;
    const int k0 = rowptr[d], k1 = rowptr[d + 1];
    const float erh = er[(size_t)d * 4 + h];
    float a0 = 0.f, a1 = 0.f, den = 0.f;

    int kb = k0;
    for (; kb + 8 <= k1; kb += 8) {
        int s0 = srt[kb + half];
        int s1 = srt[kb + 2 + half];
        int s2 = srt[kb + 4 + half];
        int s3 = srt[kb + 6 + half];
        float e0 = el[(size_t)s0 * 4 + h];
        float e1 = el[(size_t)s1 * 4 + h];
        float e2 = el[(size_t)s2 * 4 + h];
        float e3 = el[(size_t)s3 * 4 + h];
        unsigned int f0 = *(const unsigned int*)(fsb + (size_t)s0 * O_OUT + 2 * c);
        unsigned int f1 = *(const unsigned int*)(fsb + (size_t)s1 * O_OUT + 2 * c);
        unsigned int f2 = *(const unsigned int*)(fsb + (size_t)s2 * O_OUT + 2 * c);
        unsigned int f3 = *(const unsigned int*)(fsb + (size_t)s3 * O_OUT + 2 * c);
        float w0 = __expf(lrelu(e0 + erh));
        float w1 = __expf(lrelu(e1 + erh));
        float w2 = __expf(lrelu(e2 + erh));
        float w3 = __expf(lrelu(e3 + erh));
        a0 += w0 * bflo(f0); a1 += w0 * bfhi(f0); den += w0;
        a0 += w1 * bflo(f1); a1 += w1 * bfhi(f1); den += w1;
        a0 += w2 * bflo(f2); a1 += w2 * bfhi(f2); den += w2;
        a0 += w3 * bflo(f3); a1 += w3 * bfhi(f3); den += w3;
    }
    for (; kb < k1; kb += 2) {
        int ki = kb + half;
        if (ki < k1) {
            int s = srt[ki];
            float w = __expf(lrelu(el[(size_t)s * 4 + h] + erh));
            unsigned int f = *(const unsigned int*)(fsb + (size_t)s * O_OUT + 2 * c);
            a0 += w * bflo(f); a1 += w * bfhi(f); den += w;
        }
    }
    a0 += __shfl_xor(a0, 32);
    a1 += __shfl_xor(a1, 32);
    den += __shfl_xor(den, 32);
    if (half == 0) {
        float inv = 1.0f / fmaxf(den, 1e-20f);
        float2* po = (float2*)(out + (size_t)d * O_OUT + 2 * c);
        float2 o = *po;
        o.x += a0 * inv;
        o.y += a1 * inv;
        *po = o;
    }
}

// ---------------------------------------------------------------------------
// Fallback path (small ws): no-max softmax, atomics, bf16 fs.
// ---------------------------------------------------------------------------
__global__ __launch_bounds__(256) void edge_sum_kernel(
    const int* __restrict__ src, const int* __restrict__ dst,
    const float* __restrict__ el, const float* __restrict__ er,
    float* __restrict__ denom, int E)
{
    int e = blockIdx.x * 256 + threadIdx.x;
    if (e >= E) return;
    int s = src[e], d = dst[e];
    float4 l4 = ((const float4*)el)[s];
    float4 r4 = ((const float4*)er)[d];
    unsafeAtomicAdd(&denom[(size_t)d * 4 + 0], __expf(lrelu(l4.x + r4.x)));
    unsafeAtomicAdd(&denom[(size_t)d * 4 + 1], __expf(lrelu(l4.y + r4.y)));
    unsafeAtomicAdd(&denom[(size_t)d * 4 + 2], __expf(lrelu(l4.z + r4.z)));
    unsafeAtomicAdd(&denom[(size_t)d * 4 + 3], __expf(lrelu(l4.w + r4.w)));
}

__global__ __launch_bounds__(256) void agg_atomic_kernel(
    const int* __restrict__ src, const int* __restrict__ dst,
    const unsigned short* __restrict__ fsb, const float* __restrict__ el,
    const float* __restrict__ er, const float* __restrict__ denom,
    float* __restrict__ out, int E)
{
    const int lane = threadIdx.x & 63;
    const int wid = threadIdx.x >> 6;
    int e = blockIdx.x * 4 + wid;
    if (e >= E) return;
    int s = src[e], d = dst[e];
    int h = lane >> 4;
    float v = __expf(lrelu(el[(size_t)s * 4 + h] + er[(size_t)d * 4 + h]));
    float alpha = v / fmaxf(denom[(size_t)d * 4 + h], 1e-20f);
    float fval = __uint_as_float(((unsigned int)fsb[(size_t)s * O_OUT + lane]) << 16);
    unsafeAtomicAdd(&out[(size_t)d * O_OUT + lane], alpha * fval);
}

extern "C" void kernel_launch(void* const* d_in, const int* in_sizes, int n_in,
                              void* d_out, int out_size, void* d_ws, size_t ws_size,
                              hipStream_t stream) {
    const float* feat   = (const float*)d_in[0];
    const float* Wfc    = (const float*)d_in[1];
    const float* attn_l = (const float*)d_in[2];
    const float* attn_r = (const float*)d_in[3];
    const float* Wres   = (const float*)d_in[4];
    const int*   src    = (const int*)d_in[5];
    const int*   dst    = (const int*)d_in[6];

    const int N = in_sizes[0] / F_IN;     // 100000
    const int E = in_sizes[5];            // 3200000
    float* out = (float*)d_out;

    // layout: el | er | Bf | count[N] | rowptr[N+4] | bsums[1024] |
    //         sorted_src[E] | fsb
    float* el     = (float*)d_ws;
    float* er     = el + (size_t)N * 4;
    unsigned short* Bf = (unsigned short*)(er + (size_t)N * 4);
    int*   count  = (int*)(Bf + 32768);
    int*   rowptr = count + N;
    int*   bsums  = rowptr + N + 4;
    int*   sorted_src = bsums + 1024;
    unsigned short* fsb = (unsigned short*)(sorted_src + E);
    size_t need_main = (size_t)((char*)(fsb + (size_t)N * O_OUT) - (char*)d_ws);

    int nproj = (N + 63) / 64;
    int nsb = (N + 1023) / 1024;          // scan blocks over count[N]

    if (ws_size >= need_main && nsb <= 1024) {
        wprep_kernel<<<16, 256, 0, stream>>>(Wfc, Wres, Bf);
        proj_mfma_kernel<<<nproj, 256, 0, stream>>>(
            feat, Bf, attn_l, attn_r, fsb, el, er, out, nullptr, N);
        zero_kernel<<<(N + 255) / 256, 256, 0, stream>>>(count, N);
        hist_kernel<<<(E + 255) / 256, 256, 0, stream>>>(dst, count, E);
        scan_block_kernel<<<nsb, 256, 0, stream>>>(count, rowptr, bsums, N);
        scan_bsums_kernel<<<1, 64, 0, stream>>>(bsums, nsb);
        scan_final_kernel<<<(N + 255) / 256, 256, 0, stream>>>(rowptr, bsums, N, E);
        scatter_csr_kernel<<<(E + 255) / 256, 256, 0, stream>>>(
            src, dst, rowptr, count, sorted_src, E);
        agg_csr_kernel<<<(N + 3) / 4, 256, 0, stream>>>(
            rowptr, sorted_src, fsb, el, er, out, N);
    } else {
        // fallback: denom overlays count region; fsb right after denom
        float* denom = (float*)count;                 // [N*4]
        unsigned short* fsb2 = (unsigned short*)(denom + (size_t)N * 4);
        wprep_kernel<<<16, 256, 0, stream>>>(Wfc, Wres, Bf);
        proj_mfma_kernel<<<nproj, 256, 0, stream>>>(
            feat, Bf, attn_l, attn_r, fsb2, el, er, out, denom, N);
        edge_sum_kernel<<<(E + 255) / 256, 256, 0, stream>>>(src, dst, el, er, denom, E);
        agg_atomic_kernel<<<(E + 3) / 4, 256, 0, stream>>>(
            src, dst, fsb2, el, er, denom, out, E);
    }
}